// Round 6
// baseline (369.265 us; speedup 1.0000x reference)
//
#include <hip/hip_runtime.h>
#include <math.h>

// N nodes (50000), E edges (600000), D=128.
// Q = x@Wq.T; K = x@Wk.T; V = x@Wv.T  (node-level)
// per edge e=(s->d): c = sigmoid(dot(Q[d],K[s])/sqrt(128)); agg[d] += c*V[s]
// out = LN(x + agg@Wo.T + bo) * gamma + beta
//
// R2: f32 atomics hit TCC atomic ceiling -> counting-sort + per-node agg.
// R3: fp32 VALU GEMMs -> split-bf16 MFMA (C = xh*wh + xl*wh + xh*wl).
// R4: K/V bf16 (halved gather bytes, 25.6 MB working set).
// R5: node_agg VALU-issue-heavy + remainder-path serialization ->
//     KV element-interleaved (1 load/edge/lane), ds_swizzle reduce (no addr
//     VALU), masked full-width batches; 10 -> 7 dispatches (fused zero+prep,
//     single-block scan, no blockSums).

#define BM 64
#define NB 8

typedef __attribute__((ext_vector_type(8))) short bfrag;   // 8 bf16 = 4 VGPRs
typedef __attribute__((ext_vector_type(4))) float f32x4;

__device__ __forceinline__ short f2bf(float f) {
    union { float f; unsigned u; } v; v.f = f;
    unsigned r = v.u + 0x7FFFu + ((v.u >> 16) & 1u);   // round-to-nearest-even
    return (short)(r >> 16);
}
__device__ __forceinline__ float bf2f(short h) {
    union { unsigned u; float f; } v;
    v.u = ((unsigned)(unsigned short)h) << 16;
    return v.f;
}
// unpack packed pair of bf16 (low ushort = low addr) to two floats
__device__ __forceinline__ float2 bfpair(unsigned w) {
    union { unsigned u; float f; } lo, hi;
    lo.u = w << 16;
    hi.u = w & 0xffff0000u;
    return make_float2(lo.f, hi.f);
}

// ---------- fused: zero hist (NPAD ints) + weight split fp32->bf16 hi/lo ----
__global__ __launch_bounds__(256) void zero_prep(
    const float* __restrict__ Wq, const float* __restrict__ Wk,
    const float* __restrict__ Wv, const float* __restrict__ Wo,
    short* __restrict__ whi, short* __restrict__ wlo,
    int* __restrict__ hist, int NPAD)
{
    int g = blockIdx.x * 256 + threadIdx.x;
    if (g < NPAD) hist[g] = 0;
    if (g < 65536) {
        const float* Ws[4] = {Wq, Wk, Wv, Wo};
        float f = Ws[g >> 14][g & 16383];
        short h = f2bf(f);
        short l = f2bf(f - bf2f(h));
        whi[g] = h; wlo[g] = l;
    }
}

// ---------------- fused QKV projection via split-bf16 MFMA ----------------
// Q written fp32; K,V written element-interleaved bf16:
// KV16[node*256 + 2*i + 0] = K[node][i], KV16[node*256 + 2*i + 1] = V[node][i]
__global__ __launch_bounds__(256) void qkv_mfma(
    const float* __restrict__ x,
    const short* __restrict__ whi, const short* __restrict__ wlo,
    float* __restrict__ Q, unsigned short* __restrict__ KV16, int N)
{
    __shared__ short xs_hi[64][136];   // +8 pad: row 272 B -> 2-way LDS (free)
    __shared__ short xs_lo[64][136];

    const int tid = threadIdx.x;
    const int row0 = blockIdx.x * BM;

    #pragma unroll
    for (int i = 0; i < 8; ++i) {
        int idx = tid + 256 * i;
        int r = idx >> 5;
        int c4 = idx & 31;
        int gr = row0 + r;
        float4 val = make_float4(0.f, 0.f, 0.f, 0.f);
        if (gr < N) val = ((const float4*)(x + (size_t)gr * 128))[c4];
        short4 h, l;
        h.x = f2bf(val.x); l.x = f2bf(val.x - bf2f(h.x));
        h.y = f2bf(val.y); l.y = f2bf(val.y - bf2f(h.y));
        h.z = f2bf(val.z); l.z = f2bf(val.z - bf2f(h.z));
        h.w = f2bf(val.w); l.w = f2bf(val.w - bf2f(h.w));
        *((short4*)&xs_hi[r][c4 * 4]) = h;
        *((short4*)&xs_lo[r][c4 * 4]) = l;
    }
    __syncthreads();

    const int wid  = tid >> 6;
    const int lane = tid & 63;
    const int n16  = lane & 15;
    const int quad = lane >> 4;

    #pragma unroll 1
    for (int mat = 0; mat < 3; ++mat) {
        const short* __restrict__ WH = whi + mat * 16384;
        const short* __restrict__ WL = wlo + mat * 16384;
        const f32x4 zero = {0.f, 0.f, 0.f, 0.f};
        f32x4 acc[4][2];
        #pragma unroll
        for (int t = 0; t < 4; ++t) { acc[t][0] = zero; acc[t][1] = zero; }

        #pragma unroll
        for (int kc = 0; kc < 4; ++kc) {
            int k0 = kc * 32 + quad * 8;
            bfrag ah[4], al[4], bh[2], bl[2];
            #pragma unroll
            for (int t = 0; t < 4; ++t) {
                ah[t] = *((const bfrag*)&xs_hi[t * 16 + n16][k0]);
                al[t] = *((const bfrag*)&xs_lo[t * 16 + n16][k0]);
            }
            #pragma unroll
            for (int c = 0; c < 2; ++c) {
                int wr = (wid * 2 + c) * 16 + n16;
                bh[c] = *((const bfrag*)(WH + wr * 128 + k0));
                bl[c] = *((const bfrag*)(WL + wr * 128 + k0));
            }
            #pragma unroll
            for (int t = 0; t < 4; ++t)
                #pragma unroll
                for (int c = 0; c < 2; ++c) {
                    acc[t][c] = __builtin_amdgcn_mfma_f32_16x16x32_bf16(ah[t], bh[c], acc[t][c], 0, 0, 0);
                    acc[t][c] = __builtin_amdgcn_mfma_f32_16x16x32_bf16(al[t], bh[c], acc[t][c], 0, 0, 0);
                    acc[t][c] = __builtin_amdgcn_mfma_f32_16x16x32_bf16(ah[t], bl[c], acc[t][c], 0, 0, 0);
                }
        }
        #pragma unroll
        for (int t = 0; t < 4; ++t)
            #pragma unroll
            for (int r = 0; r < 4; ++r) {
                int grow = row0 + t * 16 + quad * 4 + r;
                if (grow < N) {
                    int c0 = (wid * 2 + 0) * 16 + n16;
                    int c1 = (wid * 2 + 1) * 16 + n16;
                    if (mat == 0) {
                        Q[(size_t)grow * 128 + c0] = acc[t][0][r];
                        Q[(size_t)grow * 128 + c1] = acc[t][1][r];
                    } else {
                        size_t base = (size_t)grow * 256 + (mat - 1);  // K at +0, V at +1
                        KV16[base + 2 * c0] = (unsigned short)f2bf(acc[t][0][r]);
                        KV16[base + 2 * c1] = (unsigned short)f2bf(acc[t][1][r]);
                    }
                }
            }
    }
}

// ---------------- counting sort of edges by dst ----------------
__global__ __launch_bounds__(256) void hist_kernel(
    const int* __restrict__ ei, int* __restrict__ hist, int E)
{
    int e = blockIdx.x * blockDim.x + threadIdx.x;
    if (e < E) atomicAdd(&hist[ei[E + e]], 1);
}

// single-block exclusive scan over NPAD (mult of 1024) padded-zero hist.
// writes identical global exclusive-scan values to offs (atomic working copy
// for scatter) and starts (read-only copy for node_agg).
__global__ __launch_bounds__(256) void scan_all(
    const int* __restrict__ hist, int* __restrict__ offs,
    int* __restrict__ starts, int NPAD)
{
    __shared__ int tsum[256];
    const int t = threadIdx.x;
    const int C = NPAD >> 8;          // per-thread chunk, multiple of 4
    const int c0 = t * C;
    int local = 0;
    for (int j = 0; j < C; j += 4) {
        int4 v = *((const int4*)(hist + c0 + j));
        local += v.x + v.y + v.z + v.w;
    }
    tsum[t] = local;
    __syncthreads();
    for (int off = 1; off < 256; off <<= 1) {
        int xv = (t >= off) ? tsum[t - off] : 0;
        __syncthreads();
        tsum[t] += xv;
        __syncthreads();
    }
    int run = tsum[t] - local;        // exclusive prefix of this thread's chunk
    for (int j = 0; j < C; ++j) {
        int idx = c0 + j;
        offs[idx] = run;
        starts[idx] = run;
        run += hist[idx];
    }
}

// scatter: offs[d] consumed (becomes END offset after all increments)
__global__ __launch_bounds__(256) void scatter_kernel(
    const int* __restrict__ ei, int* __restrict__ offs,
    int* __restrict__ ssrc, int E)
{
    int e = blockIdx.x * blockDim.x + threadIdx.x;
    if (e < E) {
        int d = ei[E + e];
        int pos = atomicAdd(&offs[d], 1);
        ssrc[pos] = ei[e];
    }
}

// ---------------- per-node attention aggregation (no atomics) ----------------
// one wave per dst node; lane covers elements {2l, 2l+1}; KV interleaved ->
// ONE dwordx2 load per edge per lane. Masked full-width batches (clamped
// index, zeroed coefficient) so every edge takes the 8-deep MLP path.
// Reduce: 5x ds_swizzle (within-32, zero addr VALU) + 1 cross-half shfl.
__global__ __launch_bounds__(256) void node_agg(
    const int* __restrict__ ssrc,
    const int* __restrict__ starts,
    const int* __restrict__ endoffs,
    const float* __restrict__ Q, const unsigned short* __restrict__ KV16,
    float* __restrict__ agg, int N)
{
    int node = blockIdx.x * 4 + (threadIdx.x >> 6);
    int lane = threadIdx.x & 63;
    if (node >= N) return;
    int start = starts[node];
    int end = endoffs[node];
    float2 q = *((const float2*)(Q + (size_t)node * 128 + lane * 2));
    float a0 = 0.f, a1 = 0.f;

    for (int i = start; i < end; i += NB) {
        int s[NB];
        #pragma unroll
        for (int j = 0; j < NB; ++j) {
            int idx = i + j;
            idx = (idx < end) ? idx : (end - 1);   // clamp: dup load, c zeroed
            s[j] = ssrc[idx];
        }
        uint2 w[NB];
        #pragma unroll
        for (int j = 0; j < NB; ++j)
            w[j] = *((const uint2*)(KV16 + (size_t)s[j] * 256 + lane * 4));
        float p[NB];
        #pragma unroll
        for (int j = 0; j < NB; ++j) {
            float2 kv0 = bfpair(w[j].x);   // (k_{2l}, v_{2l})
            float2 kv1 = bfpair(w[j].y);   // (k_{2l+1}, v_{2l+1})
            p[j] = q.x * kv0.x + q.y * kv1.x;
        }
        // butterfly: 5 swizzle steps within 32-lane groups (imm patterns:
        // (xor<<10)|0x1F), then one cross-half xor-32 via shfl.
        #pragma unroll
        for (int j = 0; j < NB; ++j)
            p[j] += __int_as_float(__builtin_amdgcn_ds_swizzle(__float_as_int(p[j]), 0x041F));
        #pragma unroll
        for (int j = 0; j < NB; ++j)
            p[j] += __int_as_float(__builtin_amdgcn_ds_swizzle(__float_as_int(p[j]), 0x081F));
        #pragma unroll
        for (int j = 0; j < NB; ++j)
            p[j] += __int_as_float(__builtin_amdgcn_ds_swizzle(__float_as_int(p[j]), 0x101F));
        #pragma unroll
        for (int j = 0; j < NB; ++j)
            p[j] += __int_as_float(__builtin_amdgcn_ds_swizzle(__float_as_int(p[j]), 0x201F));
        #pragma unroll
        for (int j = 0; j < NB; ++j)
            p[j] += __int_as_float(__builtin_amdgcn_ds_swizzle(__float_as_int(p[j]), 0x401F));
        #pragma unroll
        for (int j = 0; j < NB; ++j)
            p[j] += __shfl_xor(p[j], 32);

        #pragma unroll
        for (int j = 0; j < NB; ++j) {
            float c = 1.f / (1.f + __expf(-p[j] * 0.0883883476483184f));
            if (i + j >= end) c = 0.f;
            float2 kv0 = bfpair(w[j].x);
            float2 kv1 = bfpair(w[j].y);
            a0 += c * kv0.y; a1 += c * kv1.y;
        }
    }
    *((float2*)(agg + (size_t)node * 128 + lane * 2)) = make_float2(a0, a1);
}

// ------- output GEMM (split-bf16 MFMA) + bias + residual + LayerNorm -------
__global__ __launch_bounds__(256) void out_ln_mfma(
    const float* __restrict__ agg,
    const short* __restrict__ whi, const short* __restrict__ wlo,  // Wo = mat 3
    const float* __restrict__ bo, const float* __restrict__ x,
    const float* __restrict__ gamma, const float* __restrict__ beta,
    float* __restrict__ out, int N)
{
    __shared__ __align__(16) char smem[64 * 136 * 2 * 2];   // 69632 B
    short (*xs_hi)[136] = (short(*)[136])smem;
    short (*xs_lo)[136] = (short(*)[136])(smem + 64 * 136 * 2);
    float (*hs)[132]    = (float(*)[132])smem;               // reused post-GEMM

    const int tid = threadIdx.x;
    const int row0 = blockIdx.x * BM;

    #pragma unroll
    for (int i = 0; i < 8; ++i) {
        int idx = tid + 256 * i;
        int r = idx >> 5;
        int c4 = idx & 31;
        int gr = row0 + r;
        float4 val = make_float4(0.f, 0.f, 0.f, 0.f);
        if (gr < N) val = ((const float4*)(agg + (size_t)gr * 128))[c4];
        short4 h, l;
        h.x = f2bf(val.x); l.x = f2bf(val.x - bf2f(h.x));
        h.y = f2bf(val.y); l.y = f2bf(val.y - bf2f(h.y));
        h.z = f2bf(val.z); l.z = f2bf(val.z - bf2f(h.z));
        h.w = f2bf(val.w); l.w = f2bf(val.w - bf2f(h.w));
        *((short4*)&xs_hi[r][c4 * 4]) = h;
        *((short4*)&xs_lo[r][c4 * 4]) = l;
    }
    __syncthreads();

    const int wid  = tid >> 6;
    const int lane = tid & 63;
    const int n16  = lane & 15;
    const int quad = lane >> 4;
    const short* __restrict__ WH = whi + 3 * 16384;
    const short* __restrict__ WL = wlo + 3 * 16384;

    const f32x4 zero = {0.f, 0.f, 0.f, 0.f};
    f32x4 acc[4][2];
    #pragma unroll
    for (int t = 0; t < 4; ++t) { acc[t][0] = zero; acc[t][1] = zero; }

    #pragma unroll
    for (int kc = 0; kc < 4; ++kc) {
        int k0 = kc * 32 + quad * 8;
        bfrag ah[4], al[4], bh[2], bl[2];
        #pragma unroll
        for (int t = 0; t < 4; ++t) {
            ah[t] = *((const bfrag*)&xs_hi[t * 16 + n16][k0]);
            al[t] = *((const bfrag*)&xs_lo[t * 16 + n16][k0]);
        }
        #pragma unroll
        for (int c = 0; c < 2; ++c) {
            int wr = (wid * 2 + c) * 16 + n16;
            bh[c] = *((const bfrag*)(WH + wr * 128 + k0));
            bl[c] = *((const bfrag*)(WL + wr * 128 + k0));
        }
        #pragma unroll
        for (int t = 0; t < 4; ++t)
            #pragma unroll
            for (int c = 0; c < 2; ++c) {
                acc[t][c] = __builtin_amdgcn_mfma_f32_16x16x32_bf16(ah[t], bh[c], acc[t][c], 0, 0, 0);
                acc[t][c] = __builtin_amdgcn_mfma_f32_16x16x32_bf16(al[t], bh[c], acc[t][c], 0, 0, 0);
                acc[t][c] = __builtin_amdgcn_mfma_f32_16x16x32_bf16(ah[t], bl[c], acc[t][c], 0, 0, 0);
            }
    }
    __syncthreads();   // all xs reads done before hs overwrite

    #pragma unroll
    for (int t = 0; t < 4; ++t)
        #pragma unroll
        for (int r = 0; r < 4; ++r) {
            hs[t * 16 + quad * 4 + r][(wid * 2 + 0) * 16 + n16] = acc[t][0][r];
            hs[t * 16 + quad * 4 + r][(wid * 2 + 1) * 16 + n16] = acc[t][1][r];
        }
    __syncthreads();

    {
        int r = tid >> 2;
        int qd = tid & 3;
        int gr = row0 + r;
        float sum = 0.f, sq = 0.f;
        #pragma unroll
        for (int c = 0; c < 32; c += 4) {
            float4 g4 = *((float4*)&hs[r][qd * 32 + c]);
            float4 b4 = *((const float4*)(bo + qd * 32 + c));
            float4 x4 = make_float4(0.f, 0.f, 0.f, 0.f);
            if (gr < N) x4 = *((const float4*)(x + (size_t)gr * 128 + qd * 32 + c));
            float4 h = make_float4(g4.x + b4.x + x4.x, g4.y + b4.y + x4.y,
                                   g4.z + b4.z + x4.z, g4.w + b4.w + x4.w);
            *((float4*)&hs[r][qd * 32 + c]) = h;
            sum += h.x + h.y + h.z + h.w;
            sq += h.x * h.x + h.y * h.y + h.z * h.z + h.w * h.w;
        }
        sum += __shfl_xor(sum, 1); sum += __shfl_xor(sum, 2);
        sq  += __shfl_xor(sq, 1);  sq  += __shfl_xor(sq, 2);
        float mu = sum * (1.f / 128.f);
        float var = sq * (1.f / 128.f) - mu * mu;
        float rs = rsqrtf(var + 1e-5f);
        if (gr < N) {
            #pragma unroll
            for (int c = 0; c < 32; c += 4) {
                float4 h = *((float4*)&hs[r][qd * 32 + c]);
                float4 g = *((const float4*)(gamma + qd * 32 + c));
                float4 b = *((const float4*)(beta + qd * 32 + c));
                float4 o = make_float4((h.x - mu) * rs * g.x + b.x,
                                       (h.y - mu) * rs * g.y + b.y,
                                       (h.z - mu) * rs * g.z + b.z,
                                       (h.w - mu) * rs * g.w + b.w);
                *((float4*)(out + (size_t)gr * 128 + qd * 32 + c)) = o;
            }
        }
    }
}

extern "C" void kernel_launch(void* const* d_in, const int* in_sizes, int n_in,
                              void* d_out, int out_size, void* d_ws, size_t ws_size,
                              hipStream_t stream) {
    const float* x     = (const float*)d_in[0];
    const int*   ei    = (const int*)d_in[1];
    const float* Wq    = (const float*)d_in[2];
    const float* Wk    = (const float*)d_in[3];
    const float* Wv    = (const float*)d_in[4];
    const float* Wo    = (const float*)d_in[5];
    const float* bo    = (const float*)d_in[6];
    const float* gamma = (const float*)d_in[7];
    const float* beta  = (const float*)d_in[8];
    const int N = in_sizes[0] / 128;
    const int E = in_sizes[1] / 2;
    const size_t ND = (size_t)N * 128;
    const int NPAD = ((N + 1023) / 1024) * 1024;   // mult of 1024 for scan_all

    // workspace: Q fp32 25.6MB + KV16 interleaved bf16 25.6MB + agg 25.6MB
    //            + hist/offs/starts (NPAD ints each) + ssrc (E) + whi/wlo
    float* ws  = (float*)d_ws;
    float* Q   = ws;
    unsigned short* KV16 = (unsigned short*)(Q + ND);    // 2*ND ushorts
    float* agg = (float*)(KV16 + 2 * ND);
    int* hist   = (int*)(agg + ND);
    int* offs   = hist + NPAD;
    int* starts = offs + NPAD;
    int* ssrc   = starts + NPAD;                // E ints
    short* whi  = (short*)(ssrc + E);           // 4*16384 shorts
    short* wlo  = whi + 4 * 16384;

    const int gzp = ((NPAD > 65536 ? NPAD : 65536) + 255) / 256;
    zero_prep<<<gzp, 256, 0, stream>>>(Wq, Wk, Wv, Wo, whi, wlo, hist, NPAD);

    hist_kernel<<<(E + 255) / 256, 256, 0, stream>>>(ei, hist, E);
    scan_all<<<1, 256, 0, stream>>>(hist, offs, starts, NPAD);
    scatter_kernel<<<(E + 255) / 256, 256, 0, stream>>>(ei, offs, ssrc, E);

    const int gq = (N + BM - 1) / BM;
    qkv_mfma<<<gq, 256, 0, stream>>>(x, whi, wlo, Q, KV16, N);

    node_agg<<<(N + 3) / 4, 256, 0, stream>>>(ssrc, starts, offs, Q, KV16, agg, N);

    out_ln_mfma<<<gq, 256, 0, stream>>>(agg, whi, wlo, bo, x, gamma, beta,
                                        (float*)d_out, N);
}

// Round 7
// 276.646 us; speedup vs baseline: 1.3348x; 1.3348x over previous
//
#include <hip/hip_runtime.h>
#include <math.h>

// N nodes (50000), E edges (600000), D=128.
// Q = x@Wq.T; K = x@Wk.T; V = x@Wv.T  (node-level)
// per edge e=(s->d): c = sigmoid(dot(Q[d],K[s])/sqrt(128)); agg[d] += c*V[s]
// out = LN(x + agg@Wo.T + bo) * gamma + beta
//
// R2: f32 atomics hit TCC atomic ceiling -> counting-sort + per-node agg.
// R3: fp32 VALU GEMMs -> split-bf16 MFMA (C = xh*wh + xl*wh + xh*wl).
// R4: K/V bf16 (halved gather bytes, 25.6 MB working set).
// R5: node_agg KV-interleaved (1 dwordx2/edge/lane), ds_swizzle reduce,
//     masked full-width batches.
// R6: single-block scan was a 103 us latency chain (1 CU, dependent loads)
//     -> revert to multi-block 3-kernel scan (R4-proven, few us each).

#define BM 64
#define NB 8

typedef __attribute__((ext_vector_type(8))) short bfrag;   // 8 bf16 = 4 VGPRs
typedef __attribute__((ext_vector_type(4))) float f32x4;

__device__ __forceinline__ short f2bf(float f) {
    union { float f; unsigned u; } v; v.f = f;
    unsigned r = v.u + 0x7FFFu + ((v.u >> 16) & 1u);   // round-to-nearest-even
    return (short)(r >> 16);
}
__device__ __forceinline__ float bf2f(short h) {
    union { unsigned u; float f; } v;
    v.u = ((unsigned)(unsigned short)h) << 16;
    return v.f;
}
// unpack packed pair of bf16 (low ushort = low addr) to two floats
__device__ __forceinline__ float2 bfpair(unsigned w) {
    union { unsigned u; float f; } lo, hi;
    lo.u = w << 16;
    hi.u = w & 0xffff0000u;
    return make_float2(lo.f, hi.f);
}

// ---------- fused: zero hist (N ints) + weight split fp32->bf16 hi/lo ----
__global__ __launch_bounds__(256) void zero_prep(
    const float* __restrict__ Wq, const float* __restrict__ Wk,
    const float* __restrict__ Wv, const float* __restrict__ Wo,
    short* __restrict__ whi, short* __restrict__ wlo,
    int* __restrict__ hist, int N)
{
    int g = blockIdx.x * 256 + threadIdx.x;
    if (g < N) hist[g] = 0;
    if (g < 65536) {
        const float* Ws[4] = {Wq, Wk, Wv, Wo};
        float f = Ws[g >> 14][g & 16383];
        short h = f2bf(f);
        short l = f2bf(f - bf2f(h));
        whi[g] = h; wlo[g] = l;
    }
}

// ---------------- fused QKV projection via split-bf16 MFMA ----------------
// Q written fp32; K,V written element-interleaved bf16:
// KV16[node*256 + 2*i + 0] = K[node][i], KV16[node*256 + 2*i + 1] = V[node][i]
__global__ __launch_bounds__(256) void qkv_mfma(
    const float* __restrict__ x,
    const short* __restrict__ whi, const short* __restrict__ wlo,
    float* __restrict__ Q, unsigned short* __restrict__ KV16, int N)
{
    __shared__ short xs_hi[64][136];   // +8 pad: row 272 B -> 2-way LDS (free)
    __shared__ short xs_lo[64][136];

    const int tid = threadIdx.x;
    const int row0 = blockIdx.x * BM;

    #pragma unroll
    for (int i = 0; i < 8; ++i) {
        int idx = tid + 256 * i;
        int r = idx >> 5;
        int c4 = idx & 31;
        int gr = row0 + r;
        float4 val = make_float4(0.f, 0.f, 0.f, 0.f);
        if (gr < N) val = ((const float4*)(x + (size_t)gr * 128))[c4];
        short4 h, l;
        h.x = f2bf(val.x); l.x = f2bf(val.x - bf2f(h.x));
        h.y = f2bf(val.y); l.y = f2bf(val.y - bf2f(h.y));
        h.z = f2bf(val.z); l.z = f2bf(val.z - bf2f(h.z));
        h.w = f2bf(val.w); l.w = f2bf(val.w - bf2f(h.w));
        *((short4*)&xs_hi[r][c4 * 4]) = h;
        *((short4*)&xs_lo[r][c4 * 4]) = l;
    }
    __syncthreads();

    const int wid  = tid >> 6;
    const int lane = tid & 63;
    const int n16  = lane & 15;
    const int quad = lane >> 4;

    #pragma unroll 1
    for (int mat = 0; mat < 3; ++mat) {
        const short* __restrict__ WH = whi + mat * 16384;
        const short* __restrict__ WL = wlo + mat * 16384;
        const f32x4 zero = {0.f, 0.f, 0.f, 0.f};
        f32x4 acc[4][2];
        #pragma unroll
        for (int t = 0; t < 4; ++t) { acc[t][0] = zero; acc[t][1] = zero; }

        #pragma unroll
        for (int kc = 0; kc < 4; ++kc) {
            int k0 = kc * 32 + quad * 8;
            bfrag ah[4], al[4], bh[2], bl[2];
            #pragma unroll
            for (int t = 0; t < 4; ++t) {
                ah[t] = *((const bfrag*)&xs_hi[t * 16 + n16][k0]);
                al[t] = *((const bfrag*)&xs_lo[t * 16 + n16][k0]);
            }
            #pragma unroll
            for (int c = 0; c < 2; ++c) {
                int wr = (wid * 2 + c) * 16 + n16;
                bh[c] = *((const bfrag*)(WH + wr * 128 + k0));
                bl[c] = *((const bfrag*)(WL + wr * 128 + k0));
            }
            #pragma unroll
            for (int t = 0; t < 4; ++t)
                #pragma unroll
                for (int c = 0; c < 2; ++c) {
                    acc[t][c] = __builtin_amdgcn_mfma_f32_16x16x32_bf16(ah[t], bh[c], acc[t][c], 0, 0, 0);
                    acc[t][c] = __builtin_amdgcn_mfma_f32_16x16x32_bf16(al[t], bh[c], acc[t][c], 0, 0, 0);
                    acc[t][c] = __builtin_amdgcn_mfma_f32_16x16x32_bf16(ah[t], bl[c], acc[t][c], 0, 0, 0);
                }
        }
        #pragma unroll
        for (int t = 0; t < 4; ++t)
            #pragma unroll
            for (int r = 0; r < 4; ++r) {
                int grow = row0 + t * 16 + quad * 4 + r;
                if (grow < N) {
                    int c0 = (wid * 2 + 0) * 16 + n16;
                    int c1 = (wid * 2 + 1) * 16 + n16;
                    if (mat == 0) {
                        Q[(size_t)grow * 128 + c0] = acc[t][0][r];
                        Q[(size_t)grow * 128 + c1] = acc[t][1][r];
                    } else {
                        size_t base = (size_t)grow * 256 + (mat - 1);  // K at +0, V at +1
                        KV16[base + 2 * c0] = (unsigned short)f2bf(acc[t][0][r]);
                        KV16[base + 2 * c1] = (unsigned short)f2bf(acc[t][1][r]);
                    }
                }
            }
    }
}

// ---------------- counting sort of edges by dst ----------------
__global__ __launch_bounds__(256) void hist_kernel(
    const int* __restrict__ ei, int* __restrict__ hist, int E)
{
    int e = blockIdx.x * blockDim.x + threadIdx.x;
    if (e < E) atomicAdd(&hist[ei[E + e]], 1);
}

#define SCAN_TPB 256
#define SCAN_EPT 4   // 1024 elements per scan block

__global__ __launch_bounds__(SCAN_TPB) void scan_partial(
    const int* __restrict__ hist, int* __restrict__ offs,
    int* __restrict__ blockSums, int N)
{
    __shared__ int sdata[SCAN_TPB];
    int b = blockIdx.x;
    int t = threadIdx.x;
    int base = b * SCAN_TPB * SCAN_EPT + t * SCAN_EPT;
    int v[SCAN_EPT];
    int tot = 0;
    #pragma unroll
    for (int j = 0; j < SCAN_EPT; ++j) {
        int idx = base + j;
        v[j] = (idx < N) ? hist[idx] : 0;
        tot += v[j];
    }
    sdata[t] = tot;
    __syncthreads();
    for (int off = 1; off < SCAN_TPB; off <<= 1) {
        int xv = (t >= off) ? sdata[t - off] : 0;
        __syncthreads();
        sdata[t] += xv;
        __syncthreads();
    }
    int run = sdata[t] - tot;
    #pragma unroll
    for (int j = 0; j < SCAN_EPT; ++j) {
        int idx = base + j;
        if (idx < N) offs[idx] = run;
        run += v[j];
    }
    if (t == SCAN_TPB - 1) blockSums[b] = sdata[t];
}

__global__ __launch_bounds__(256) void scan_blocksums(int* __restrict__ blockSums, int nb)
{
    __shared__ int sdata[256];
    int t = threadIdx.x;
    int orig = (t < nb) ? blockSums[t] : 0;
    sdata[t] = orig;
    __syncthreads();
    for (int off = 1; off < 256; off <<= 1) {
        int xv = (t >= off) ? sdata[t - off] : 0;
        __syncthreads();
        sdata[t] += xv;
        __syncthreads();
    }
    if (t < nb) blockSums[t] = sdata[t] - orig;
}

// adds block prefix; writes both offs (scatter working copy) and starts (kept)
__global__ __launch_bounds__(256) void scan_add(
    int* __restrict__ offs, int* __restrict__ starts,
    const int* __restrict__ blockSums, int N)
{
    int idx = blockIdx.x * blockDim.x + threadIdx.x;
    if (idx < N) {
        int vv = offs[idx] + blockSums[idx >> 10];
        offs[idx] = vv;
        starts[idx] = vv;
    }
}

// scatter: offs[d] consumed (becomes END offset after all increments)
__global__ __launch_bounds__(256) void scatter_kernel(
    const int* __restrict__ ei, int* __restrict__ offs,
    int* __restrict__ ssrc, int E)
{
    int e = blockIdx.x * blockDim.x + threadIdx.x;
    if (e < E) {
        int d = ei[E + e];
        int pos = atomicAdd(&offs[d], 1);
        ssrc[pos] = ei[e];
    }
}

// ---------------- per-node attention aggregation (no atomics) ----------------
// one wave per dst node; lane covers elements {2l, 2l+1}; KV interleaved ->
// ONE dwordx2 load per edge per lane. Masked full-width batches (clamped
// index, zeroed coefficient) so every edge takes the 8-deep MLP path.
// Reduce: 5x ds_swizzle (within-32, zero addr VALU) + 1 cross-half shfl.
__global__ __launch_bounds__(256) void node_agg(
    const int* __restrict__ ssrc,
    const int* __restrict__ starts,
    const int* __restrict__ endoffs,
    const float* __restrict__ Q, const unsigned short* __restrict__ KV16,
    float* __restrict__ agg, int N)
{
    int node = blockIdx.x * 4 + (threadIdx.x >> 6);
    int lane = threadIdx.x & 63;
    if (node >= N) return;
    int start = starts[node];
    int end = endoffs[node];
    float2 q = *((const float2*)(Q + (size_t)node * 128 + lane * 2));
    float a0 = 0.f, a1 = 0.f;

    for (int i = start; i < end; i += NB) {
        int s[NB];
        #pragma unroll
        for (int j = 0; j < NB; ++j) {
            int idx = i + j;
            idx = (idx < end) ? idx : (end - 1);   // clamp: dup load, c zeroed
            s[j] = ssrc[idx];
        }
        uint2 w[NB];
        #pragma unroll
        for (int j = 0; j < NB; ++j)
            w[j] = *((const uint2*)(KV16 + (size_t)s[j] * 256 + lane * 4));
        float p[NB];
        #pragma unroll
        for (int j = 0; j < NB; ++j) {
            float2 kv0 = bfpair(w[j].x);   // (k_{2l}, v_{2l})
            float2 kv1 = bfpair(w[j].y);   // (k_{2l+1}, v_{2l+1})
            p[j] = q.x * kv0.x + q.y * kv1.x;
        }
        #pragma unroll
        for (int j = 0; j < NB; ++j)
            p[j] += __int_as_float(__builtin_amdgcn_ds_swizzle(__float_as_int(p[j]), 0x041F));
        #pragma unroll
        for (int j = 0; j < NB; ++j)
            p[j] += __int_as_float(__builtin_amdgcn_ds_swizzle(__float_as_int(p[j]), 0x081F));
        #pragma unroll
        for (int j = 0; j < NB; ++j)
            p[j] += __int_as_float(__builtin_amdgcn_ds_swizzle(__float_as_int(p[j]), 0x101F));
        #pragma unroll
        for (int j = 0; j < NB; ++j)
            p[j] += __int_as_float(__builtin_amdgcn_ds_swizzle(__float_as_int(p[j]), 0x201F));
        #pragma unroll
        for (int j = 0; j < NB; ++j)
            p[j] += __int_as_float(__builtin_amdgcn_ds_swizzle(__float_as_int(p[j]), 0x401F));
        #pragma unroll
        for (int j = 0; j < NB; ++j)
            p[j] += __shfl_xor(p[j], 32);

        #pragma unroll
        for (int j = 0; j < NB; ++j) {
            float c = 1.f / (1.f + __expf(-p[j] * 0.0883883476483184f));
            if (i + j >= end) c = 0.f;
            float2 kv0 = bfpair(w[j].x);
            float2 kv1 = bfpair(w[j].y);
            a0 += c * kv0.y; a1 += c * kv1.y;
        }
    }
    *((float2*)(agg + (size_t)node * 128 + lane * 2)) = make_float2(a0, a1);
}

// ------- output GEMM (split-bf16 MFMA) + bias + residual + LayerNorm -------
__global__ __launch_bounds__(256) void out_ln_mfma(
    const float* __restrict__ agg,
    const short* __restrict__ whi, const short* __restrict__ wlo,  // Wo = mat 3
    const float* __restrict__ bo, const float* __restrict__ x,
    const float* __restrict__ gamma, const float* __restrict__ beta,
    float* __restrict__ out, int N)
{
    __shared__ __align__(16) char smem[64 * 136 * 2 * 2];   // 69632 B
    short (*xs_hi)[136] = (short(*)[136])smem;
    short (*xs_lo)[136] = (short(*)[136])(smem + 64 * 136 * 2);
    float (*hs)[132]    = (float(*)[132])smem;               // reused post-GEMM

    const int tid = threadIdx.x;
    const int row0 = blockIdx.x * BM;

    #pragma unroll
    for (int i = 0; i < 8; ++i) {
        int idx = tid + 256 * i;
        int r = idx >> 5;
        int c4 = idx & 31;
        int gr = row0 + r;
        float4 val = make_float4(0.f, 0.f, 0.f, 0.f);
        if (gr < N) val = ((const float4*)(agg + (size_t)gr * 128))[c4];
        short4 h, l;
        h.x = f2bf(val.x); l.x = f2bf(val.x - bf2f(h.x));
        h.y = f2bf(val.y); l.y = f2bf(val.y - bf2f(h.y));
        h.z = f2bf(val.z); l.z = f2bf(val.z - bf2f(h.z));
        h.w = f2bf(val.w); l.w = f2bf(val.w - bf2f(h.w));
        *((short4*)&xs_hi[r][c4 * 4]) = h;
        *((short4*)&xs_lo[r][c4 * 4]) = l;
    }
    __syncthreads();

    const int wid  = tid >> 6;
    const int lane = tid & 63;
    const int n16  = lane & 15;
    const int quad = lane >> 4;
    const short* __restrict__ WH = whi + 3 * 16384;
    const short* __restrict__ WL = wlo + 3 * 16384;

    const f32x4 zero = {0.f, 0.f, 0.f, 0.f};
    f32x4 acc[4][2];
    #pragma unroll
    for (int t = 0; t < 4; ++t) { acc[t][0] = zero; acc[t][1] = zero; }

    #pragma unroll
    for (int kc = 0; kc < 4; ++kc) {
        int k0 = kc * 32 + quad * 8;
        bfrag ah[4], al[4], bh[2], bl[2];
        #pragma unroll
        for (int t = 0; t < 4; ++t) {
            ah[t] = *((const bfrag*)&xs_hi[t * 16 + n16][k0]);
            al[t] = *((const bfrag*)&xs_lo[t * 16 + n16][k0]);
        }
        #pragma unroll
        for (int c = 0; c < 2; ++c) {
            int wr = (wid * 2 + c) * 16 + n16;
            bh[c] = *((const bfrag*)(WH + wr * 128 + k0));
            bl[c] = *((const bfrag*)(WL + wr * 128 + k0));
        }
        #pragma unroll
        for (int t = 0; t < 4; ++t)
            #pragma unroll
            for (int c = 0; c < 2; ++c) {
                acc[t][c] = __builtin_amdgcn_mfma_f32_16x16x32_bf16(ah[t], bh[c], acc[t][c], 0, 0, 0);
                acc[t][c] = __builtin_amdgcn_mfma_f32_16x16x32_bf16(al[t], bh[c], acc[t][c], 0, 0, 0);
                acc[t][c] = __builtin_amdgcn_mfma_f32_16x16x32_bf16(ah[t], bl[c], acc[t][c], 0, 0, 0);
            }
    }
    __syncthreads();   // all xs reads done before hs overwrite

    #pragma unroll
    for (int t = 0; t < 4; ++t)
        #pragma unroll
        for (int r = 0; r < 4; ++r) {
            hs[t * 16 + quad * 4 + r][(wid * 2 + 0) * 16 + n16] = acc[t][0][r];
            hs[t * 16 + quad * 4 + r][(wid * 2 + 1) * 16 + n16] = acc[t][1][r];
        }
    __syncthreads();

    {
        int r = tid >> 2;
        int qd = tid & 3;
        int gr = row0 + r;
        float sum = 0.f, sq = 0.f;
        #pragma unroll
        for (int c = 0; c < 32; c += 4) {
            float4 g4 = *((float4*)&hs[r][qd * 32 + c]);
            float4 b4 = *((const float4*)(bo + qd * 32 + c));
            float4 x4 = make_float4(0.f, 0.f, 0.f, 0.f);
            if (gr < N) x4 = *((const float4*)(x + (size_t)gr * 128 + qd * 32 + c));
            float4 h = make_float4(g4.x + b4.x + x4.x, g4.y + b4.y + x4.y,
                                   g4.z + b4.z + x4.z, g4.w + b4.w + x4.w);
            *((float4*)&hs[r][qd * 32 + c]) = h;
            sum += h.x + h.y + h.z + h.w;
            sq += h.x * h.x + h.y * h.y + h.z * h.z + h.w * h.w;
        }
        sum += __shfl_xor(sum, 1); sum += __shfl_xor(sum, 2);
        sq  += __shfl_xor(sq, 1);  sq  += __shfl_xor(sq, 2);
        float mu = sum * (1.f / 128.f);
        float var = sq * (1.f / 128.f) - mu * mu;
        float rs = rsqrtf(var + 1e-5f);
        if (gr < N) {
            #pragma unroll
            for (int c = 0; c < 32; c += 4) {
                float4 h = *((float4*)&hs[r][qd * 32 + c]);
                float4 g = *((const float4*)(gamma + qd * 32 + c));
                float4 b = *((const float4*)(beta + qd * 32 + c));
                float4 o = make_float4((h.x - mu) * rs * g.x + b.x,
                                       (h.y - mu) * rs * g.y + b.y,
                                       (h.z - mu) * rs * g.z + b.z,
                                       (h.w - mu) * rs * g.w + b.w);
                *((float4*)(out + (size_t)gr * 128 + qd * 32 + c)) = o;
            }
        }
    }
}

extern "C" void kernel_launch(void* const* d_in, const int* in_sizes, int n_in,
                              void* d_out, int out_size, void* d_ws, size_t ws_size,
                              hipStream_t stream) {
    const float* x     = (const float*)d_in[0];
    const int*   ei    = (const int*)d_in[1];
    const float* Wq    = (const float*)d_in[2];
    const float* Wk    = (const float*)d_in[3];
    const float* Wv    = (const float*)d_in[4];
    const float* Wo    = (const float*)d_in[5];
    const float* bo    = (const float*)d_in[6];
    const float* gamma = (const float*)d_in[7];
    const float* beta  = (const float*)d_in[8];
    const int N = in_sizes[0] / 128;
    const int E = in_sizes[1] / 2;
    const size_t ND = (size_t)N * 128;

    // workspace: Q fp32 25.6MB + KV16 interleaved bf16 25.6MB + agg 25.6MB
    //            + hist/offs/starts + blockSums + ssrc + whi/wlo
    float* ws  = (float*)d_ws;
    float* Q   = ws;
    unsigned short* KV16 = (unsigned short*)(Q + ND);    // 2*ND ushorts
    float* agg = (float*)(KV16 + 2 * ND);
    int* hist      = (int*)(agg + ND);
    int* offs      = hist + N;
    int* starts    = offs + N;
    int* blockSums = starts + N;       // 256 ints
    int* ssrc      = blockSums + 256;  // E ints
    short* whi     = (short*)(ssrc + E);        // 4*16384 shorts
    short* wlo     = whi + 4 * 16384;

    const int gzp = ((N > 65536 ? N : 65536) + 255) / 256;
    zero_prep<<<gzp, 256, 0, stream>>>(Wq, Wk, Wv, Wo, whi, wlo, hist, N);

    hist_kernel<<<(E + 255) / 256, 256, 0, stream>>>(ei, hist, E);
    const int nScanBlocks = (N + SCAN_TPB * SCAN_EPT - 1) / (SCAN_TPB * SCAN_EPT);
    scan_partial<<<nScanBlocks, SCAN_TPB, 0, stream>>>(hist, offs, blockSums, N);
    scan_blocksums<<<1, 256, 0, stream>>>(blockSums, nScanBlocks);
    scan_add<<<(N + 255) / 256, 256, 0, stream>>>(offs, starts, blockSums, N);
    scatter_kernel<<<(E + 255) / 256, 256, 0, stream>>>(ei, offs, ssrc, E);

    const int gq = (N + BM - 1) / BM;
    qkv_mfma<<<gq, 256, 0, stream>>>(x, whi, wlo, Q, KV16, N);

    node_agg<<<(N + 3) / 4, 256, 0, stream>>>(ssrc, starts, offs, Q, KV16, agg, N);

    out_ln_mfma<<<gq, 256, 0, stream>>>(agg, whi, wlo, bo, x, gamma, beta,
                                        (float*)d_out, N);
}